// Round 2
// baseline (688.508 us; speedup 1.0000x reference)
//
#include <hip/hip_runtime.h>
#include <math.h>

// Geometry constants
#define VIEWS 512
#define NDET 736
#define NX 256
#define NY 256
#define EXTENT 2
#define SINO_LEN (VIEWS * NDET)          // 376832
#define NVOX (NX * NY)                   // 65536
#define PER_VOX (VIEWS * EXTENT)         // 1024

__device__ __constant__ float kScale = (float)(M_PI / 1024.0);

typedef int   int4v   __attribute__((ext_vector_type(4)));
typedef float float4v __attribute__((ext_vector_type(4)));

// One wave (64 lanes) per voxel, 16 elements per lane.
// R2: maximize MLP — issue ALL index loads, weight loads, and gathers
// before any consuming FMA. Nontemporal on the once-streamed idx/weight.
__global__ __launch_bounds__(256) void backproj_kernel(
    const float* __restrict__ x,      // [SINO_LEN]     ~1.47 MB, L2-resident
    const float* __restrict__ weight, // [NVOX*PER_VOX] streamed once
    const float* __restrict__ bias,   // [NVOX]
    const int*   __restrict__ indices,// [NVOX*PER_VOX] streamed once
    float*       __restrict__ out)    // [NVOX]
{
    const int lane = threadIdx.x & 63;
    const int v    = blockIdx.x * 4 + (threadIdx.x >> 6);
    const size_t base = (size_t)v * PER_VOX;

    const int4v*   ip = (const int4v*)(indices + base);
    const float4v* wp = (const float4v*)(weight + base);

    // All index loads up front (independent, in flight together)
    int4v i0 = __builtin_nontemporal_load(&ip[lane]);
    int4v i1 = __builtin_nontemporal_load(&ip[lane + 64]);
    int4v i2 = __builtin_nontemporal_load(&ip[lane + 128]);
    int4v i3 = __builtin_nontemporal_load(&ip[lane + 192]);

    // All weight loads up front (independent of everything)
    float4v w0 = __builtin_nontemporal_load(&wp[lane]);
    float4v w1 = __builtin_nontemporal_load(&wp[lane + 64]);
    float4v w2 = __builtin_nontemporal_load(&wp[lane + 128]);
    float4v w3 = __builtin_nontemporal_load(&wp[lane + 192]);

    // All 16 gathers issued before any FMA consumes them
    float g0  = x[i0.x], g1  = x[i0.y], g2  = x[i0.z], g3  = x[i0.w];
    float g4  = x[i1.x], g5  = x[i1.y], g6  = x[i1.z], g7  = x[i1.w];
    float g8  = x[i2.x], g9  = x[i2.y], g10 = x[i2.z], g11 = x[i2.w];
    float g12 = x[i3.x], g13 = x[i3.y], g14 = x[i3.z], g15 = x[i3.w];

    float s = 0.0f;
    s = fmaf(g0,  w0.x, s); s = fmaf(g1,  w0.y, s);
    s = fmaf(g2,  w0.z, s); s = fmaf(g3,  w0.w, s);
    s = fmaf(g4,  w1.x, s); s = fmaf(g5,  w1.y, s);
    s = fmaf(g6,  w1.z, s); s = fmaf(g7,  w1.w, s);
    s = fmaf(g8,  w2.x, s); s = fmaf(g9,  w2.y, s);
    s = fmaf(g10, w2.z, s); s = fmaf(g11, w2.w, s);
    s = fmaf(g12, w3.x, s); s = fmaf(g13, w3.y, s);
    s = fmaf(g14, w3.z, s); s = fmaf(g15, w3.w, s);

    // wave-64 reduction
#pragma unroll
    for (int off = 32; off > 0; off >>= 1)
        s += __shfl_down(s, off, 64);

    if (lane == 0) {
        // flip over both spatial axes = flattened index reversal
        out[NVOX - 1 - v] = bias[v] + kScale * s;
    }
}

extern "C" void kernel_launch(void* const* d_in, const int* in_sizes, int n_in,
                              void* d_out, int out_size, void* d_ws, size_t ws_size,
                              hipStream_t stream) {
    const float* x       = (const float*)d_in[0];
    const float* weight  = (const float*)d_in[1];
    const float* bias    = (const float*)d_in[2];
    const int*   indices = (const int*)d_in[3];
    float*       out     = (float*)d_out;

    const int blocks = NVOX / 4; // 4 waves/block, 1 voxel/wave
    backproj_kernel<<<blocks, 256, 0, stream>>>(x, weight, bias, indices, out);
}